// Round 6
// baseline (226.361 us; speedup 1.0000x reference)
//
#include <hip/hip_runtime.h>
#include <math.h>

// Problem constants (fixed by reference)
#define BBATCH 16
#define NPC    2048          // points per cloud
#define KNBR   16            // knn k (self appended -> 17 edges)
#define NPTS   (BBATCH*NPC)  // 32768
#define NGEMM  512           // gemm blocks (64 rows each)
#define NKNN   512           // knn blocks (64 targets each)
#define BUFCAP 512

// ---------------------------------------------------------------------------
// prep_kernel: Hd = Wdst@Wattn, Hs = Wsrc@Wattn, WP2 = Wpos@Wattn,
//              bb = bpos@Wattn + battn.  One block.
// ---------------------------------------------------------------------------
__global__ __launch_bounds__(1024) void prep_kernel(
    const float* __restrict__ Wpos, const float* __restrict__ bpos,
    const float* __restrict__ Wattn, const float* __restrict__ battn,
    const float* __restrict__ Wsrc, const float* __restrict__ Wdst,
    float* __restrict__ Hd, float* __restrict__ Hs,
    float* __restrict__ WP2, float* __restrict__ bb) {
  __shared__ float sW[4096];
  __shared__ float sD[4096];
  __shared__ float sS[4096];
  int t = threadIdx.x;
  ((float4*)sW)[t] = ((const float4*)Wattn)[t];
  ((float4*)sD)[t] = ((const float4*)Wdst)[t];
  ((float4*)sS)[t] = ((const float4*)Wsrc)[t];
  __syncthreads();
  int c = t & 63, r0 = t >> 6;  // r0 = 0..15
#pragma unroll
  for (int q = 0; q < 4; ++q) {
    int r = r0 + 16 * q;
    float ad = 0.f, as = 0.f;
    for (int d = 0; d < 64; ++d) {
      float w = sW[d * 64 + c];
      ad += sD[r * 64 + d] * w;
      as += sS[r * 64 + d] * w;
    }
    Hd[r * 64 + c] = ad;
    Hs[r * 64 + c] = as;
  }
  if (t < 64) {
    for (int rr = 0; rr < 3; ++rr) {
      float a = 0.f;
      for (int d = 0; d < 64; ++d) a += Wpos[rr * 64 + d] * sW[d * 64 + t];
      WP2[rr * 64 + t] = a;
    }
    float a = battn[t];
    for (int d = 0; d < 64; ++d) a += bpos[d] * sW[d * 64 + t];
    bb[t] = a;
  }
}

// ---------------------------------------------------------------------------
// fused_gk: two independent block families (byte-identical to the R5/R2
// passing version -- do NOT perturb knn register pressure, it spills at the
// compiler's 64-VGPR / 8-wave heuristic for 1024-thread blocks):
//   blocks 0..511    : A2 = x@Hd, S2 = x@Hs, V = x@Wval
//   blocks 512..1023 : exact fp64 16-NN, 64 targets per 1024-thread block
// ---------------------------------------------------------------------------
__global__ __launch_bounds__(1024) void fused_gk_kernel(
    const float* __restrict__ pos, const float* __restrict__ x,
    const float* __restrict__ Hd, const float* __restrict__ Hs,
    const float* __restrict__ Wval,
    int* __restrict__ nbr, float* __restrict__ A2, float* __restrict__ S2,
    float* __restrict__ V) {
  __shared__ __align__(16) char smem[65536];
  int t = threadIdx.x;
  int bid = blockIdx.x;
  int c = t & 63, g = t >> 6;

  if (bid < NGEMM) {
    // ---- gemm family: 64 rows per block, single staging + single sync ----
    float* R0 = (float*)smem;            // x tile
    float* R1 = (float*)(smem + 16384);  // Hd
    float* R2 = (float*)(smem + 32768);  // Hs
    float* R3 = (float*)(smem + 49152);  // Wval
    ((float4*)R0)[t] = ((const float4*)(x + (size_t)bid * 64 * 64))[t];
    ((float4*)R1)[t] = ((const float4*)Hd)[t];
    ((float4*)R2)[t] = ((const float4*)Hs)[t];
    ((float4*)R3)[t] = ((const float4*)Wval)[t];
    __syncthreads();

    float v0 = 0, v1 = 0, v2 = 0, v3 = 0;
    float a0 = 0, a1 = 0, a2 = 0, a3 = 0;
    float s0 = 0, s1 = 0, s2 = 0, s3 = 0;
    const float4* xr0 = (const float4*)(R0 + (g * 4 + 0) * 64);
    const float4* xr1 = (const float4*)(R0 + (g * 4 + 1) * 64);
    const float4* xr2 = (const float4*)(R0 + (g * 4 + 2) * 64);
    const float4* xr3 = (const float4*)(R0 + (g * 4 + 3) * 64);
#pragma unroll 4
    for (int k4 = 0; k4 < 16; ++k4) {
      float4 q0 = xr0[k4], q1 = xr1[k4], q2 = xr2[k4], q3 = xr3[k4];
#pragma unroll
      for (int kk = 0; kk < 4; ++kk) {
        int k = k4 * 4 + kk;
        float wv = R3[k * 64 + c];
        float wa = R1[k * 64 + c];
        float ws = R2[k * 64 + c];
        float e0 = (kk == 0) ? q0.x : (kk == 1) ? q0.y : (kk == 2) ? q0.z : q0.w;
        float e1 = (kk == 0) ? q1.x : (kk == 1) ? q1.y : (kk == 2) ? q1.z : q1.w;
        float e2 = (kk == 0) ? q2.x : (kk == 1) ? q2.y : (kk == 2) ? q2.z : q2.w;
        float e3 = (kk == 0) ? q3.x : (kk == 1) ? q3.y : (kk == 2) ? q3.z : q3.w;
        v0 += e0 * wv; v1 += e1 * wv; v2 += e2 * wv; v3 += e3 * wv;
        a0 += e0 * wa; a1 += e1 * wa; a2 += e2 * wa; a3 += e3 * wa;
        s0 += e0 * ws; s1 += e1 * ws; s2 += e2 * ws; s3 += e3 * ws;
      }
    }
    size_t o0 = ((size_t)bid * 64 + g * 4 + 0) * 64 + c;
    V[o0] = v0; A2[o0] = a0; S2[o0] = s0;
    size_t o1 = o0 + 64;  V[o1] = v1; A2[o1] = a1; S2[o1] = s1;
    size_t o2 = o0 + 128; V[o2] = v2; A2[o2] = a2; S2[o2] = s2;
    size_t o3 = o0 + 192; V[o3] = v3; A2[o3] = a3; S2[o3] = s3;
    return;
  }

  // ---- knn family: 64 targets per block ----
  int kb = bid - NGEMM;  // 0..511
  float4* pos4 = (float4*)smem;                           // 32 KB
  unsigned short* buf = (unsigned short*)(smem + 32768);  // 16 KB (16w x 512)
  int cloud = kb >> 5;  // 32 blocks per cloud
  const float* pc = pos + (size_t)cloud * NPC * 3;
  for (int p = t; p < NPC; p += 1024)
    pos4[p] = make_float4(pc[3 * p], pc[3 * p + 1], pc[3 * p + 2], 0.f);
  __syncthreads();

  int w = g, lane = c;
  for (int u = 0; u < 4; ++u) {
    int lt = u * 16 + w;  // local target 0..63
    int gi = kb * 64 + lt;
    int ti = gi & (NPC - 1);
    float4 tp = pos4[ti];
    float tx = tp.x, ty = tp.y, tz = tp.z;

    // Phase A: fp32 d^2 -> exponent bucket (self lands in bucket 0, kept)
    int bkt[32];
#pragma unroll
    for (int cc = 0; cc < 32; ++cc) {
      int j = cc * 64 + lane;
      float4 q = pos4[j];
      float dx = tx - q.x, dy = ty - q.y, dz = tz - q.z;
      float d2 = dx * dx + dy * dy + dz * dz;
      int b = (int)(__float_as_uint(d2) >> 20) - 896;
      bkt[cc] = max(0, min(255, b));
    }

    // Phase B: smallest T with count(bkt<=T) >= 17 (16 real + self)
    int lo = 0, hi = 255;
    for (int it = 0; it < 8; ++it) {
      int mid = (lo + hi) >> 1;
      int cnt = 0;
#pragma unroll
      for (int cc = 0; cc < 32; ++cc)
        cnt += (int)__popcll(__ballot(bkt[cc] <= mid));
      if (cnt >= 17) hi = mid; else lo = mid + 1;
    }
    int Tp1 = min(hi + 1, 255);

    // Phase C: atomic-free compaction (ballot + mbcnt prefix)
    int base = 0;
#pragma unroll
    for (int cc = 0; cc < 32; ++cc) {
      bool f = (bkt[cc] <= Tp1);
      unsigned long long mm = __ballot(f);
      unsigned int pre = __builtin_amdgcn_mbcnt_hi(
          (unsigned)(mm >> 32), __builtin_amdgcn_mbcnt_lo((unsigned)mm, 0u));
      if (f) {
        int p = base + (int)pre;
        if (p < BUFCAP) buf[w * BUFCAP + p] = (unsigned short)(cc * 64 + lane);
      }
      base += (int)__popcll(mm);
    }
    int n = min(base, BUFCAP);
    double txd = (double)tx, tyd = (double)ty, tzd = (double)tz;

    if (n <= 64) {
      // fp64 exact keys (bit-match numpy f64 ((dx^2+dy^2)+dz^2)), bitonic-64
      unsigned long long gb = 0xFFFFFFFFFFFFFFFFull;
      int gj = 0x40000000 + lane;
      if (lane < n) {
        int j = buf[w * BUFCAP + lane];
        if (j != ti) {
          float4 q = pos4[j];
          double dx = __dsub_rn(txd, (double)q.x);
          double dy = __dsub_rn(tyd, (double)q.y);
          double dz = __dsub_rn(tzd, (double)q.z);
          double d2 = __dadd_rn(__dadd_rn(__dmul_rn(dx, dx), __dmul_rn(dy, dy)),
                                __dmul_rn(dz, dz));
          gb = (unsigned long long)__double_as_longlong(d2);
          gj = j;
        }
      }
      for (int k = 2; k <= 64; k <<= 1) {
        for (int jj = k >> 1; jj > 0; jj >>= 1) {
          unsigned long long ob = __shfl_xor(gb, jj);
          int oj = __shfl_xor(gj, jj);
          bool keepmin = (((lane & k) == 0) == ((lane & jj) == 0));
          bool less = (ob < gb) || (ob == gb && oj < gj);
          if (keepmin == less) { gb = ob; gj = oj; }
        }
      }
      if (lane < KNBR) nbr[(size_t)gi * KNBR + lane] = gj;
    } else {
      // rare fallback: extraction over buffered set (n <= 512)
      unsigned long long kb2[8];
      int id2[8];
#pragma unroll
      for (int r = 0; r < 8; ++r) {
        int e = r * 64 + lane;
        kb2[r] = 0xFFFFFFFFFFFFFFFFull;
        id2[r] = 0x40000000 + e;
        if (e < n) {
          int j = buf[w * BUFCAP + e];
          if (j != ti) {
            float4 q = pos4[j];
            double dx = __dsub_rn(txd, (double)q.x);
            double dy = __dsub_rn(tyd, (double)q.y);
            double dz = __dsub_rn(tzd, (double)q.z);
            double d2 = __dadd_rn(
                __dadd_rn(__dmul_rn(dx, dx), __dmul_rn(dy, dy)),
                __dmul_rn(dz, dz));
            kb2[r] = (unsigned long long)__double_as_longlong(d2);
            id2[r] = j;
          }
        }
      }
      for (int r = 0; r < KNBR; ++r) {
        unsigned long long lb = kb2[0];
        int lj = id2[0];
#pragma unroll
        for (int cc = 1; cc < 8; ++cc)
          if (kb2[cc] < lb || (kb2[cc] == lb && id2[cc] < lj)) {
            lb = kb2[cc]; lj = id2[cc];
          }
        unsigned long long gb2 = lb;
        int gj2 = lj;
#pragma unroll
        for (int d = 32; d >= 1; d >>= 1) {
          unsigned long long ob = __shfl_xor(gb2, d);
          int oj = __shfl_xor(gj2, d);
          if (ob < gb2 || (ob == gb2 && oj < gj2)) { gb2 = ob; gj2 = oj; }
        }
#pragma unroll
        for (int cc = 0; cc < 8; ++cc)
          if (id2[cc] == gj2) kb2[cc] = 0xFFFFFFFFFFFFFFFFull;
        if (lane == 0) nbr[(size_t)gi * KNBR + r] = gj2;
      }
    }
  }
}

// ---------------------------------------------------------------------------
// edge: 512 threads = 8 waves, 32 targets per block, 64 blocks per cloud.
// Whole cloud's pos staged in LDS (24 KB) -> all neighbor-pos reads are
// uniform-address LDS broadcasts (free); only S2/V/A2/nbr touch global.
// Online softmax (m/den/acc) removes the lg[17]/vl[17] register arrays so
// the 34 S2/V gathers per target can stay deeply in flight.
// ---------------------------------------------------------------------------
__global__ __launch_bounds__(512) void edge_kernel(
    const float* __restrict__ pos, const int* __restrict__ nbr,
    const float* __restrict__ A2, const float* __restrict__ S2,
    const float* __restrict__ V, const float* __restrict__ WP2,
    const float* __restrict__ bbv, const float* __restrict__ Wpos,
    const float* __restrict__ bpos, float* __restrict__ out) {
  __shared__ float lp[NPC * 3];  // 24 KB, AoS (reads are uniform broadcasts)
  int t = threadIdx.x;
  int bid = blockIdx.x;          // 1024 blocks
  int cloud = bid >> 6;          // 64 blocks per cloud
  int tb = (bid & 63) * 32;      // base target within cloud
  const float4* pc4 = (const float4*)(pos + (size_t)cloud * NPC * 3);
#pragma unroll
  for (int r = 0; r < 3; ++r) ((float4*)lp)[t + 512 * r] = pc4[t + 512 * r];
  __syncthreads();

  int w = t >> 6, c = t & 63;  // 8 waves, lane = channel
  float wp0 = WP2[c], wp1 = WP2[64 + c], wp2 = WP2[128 + c], bbc = bbv[c];
  float u0 = Wpos[c], u1 = Wpos[64 + c], u2 = Wpos[128 + c], bpc = bpos[c];
  size_t cbase = (size_t)cloud * NPC;

  for (int u = 0; u < 4; ++u) {
    int ti = tb + u * 8 + w;     // local target in cloud
    size_t gi = cbase + ti;
    int jv = nbr[gi * KNBR + (c & 15)];  // lanes carry the 16 nbr indices
    float pix = lp[3 * ti], piy = lp[3 * ti + 1], piz = lp[3 * ti + 2];
    float a2 = A2[gi * 64 + c];

    float m = -1e30f, den = 0.f, acc = 0.f;
#pragma unroll
    for (int e = 0; e < 17; ++e) {
      int j = (e < 16) ? __shfl(jv, e) : ti;
      float dx = pix - lp[3 * j];
      float dy = piy - lp[3 * j + 1];
      float dz = piz - lp[3 * j + 2];
      size_t jg = cbase + j;
      float s2 = S2[jg * 64 + c];
      float v = V[jg * 64 + c];
      float lg = a2 - s2 + dx * wp0 + dy * wp1 + dz * wp2 + bbc;
      float vl = v + dx * u0 + dy * u1 + dz * u2 + bpc;
      float mn = fmaxf(m, lg);
      float sc = __expf(m - mn);
      float wgt = __expf(lg - mn);
      den = den * sc + wgt;
      acc = acc * sc + wgt * vl;
      m = mn;
    }
    out[gi * 64 + c] = acc / den;
  }
}

// ---------------------------------------------------------------------------
extern "C" void kernel_launch(void* const* d_in, const int* in_sizes, int n_in,
                              void* d_out, int out_size, void* d_ws, size_t ws_size,
                              hipStream_t stream) {
  const float* x     = (const float*)d_in[0];
  const float* pos   = (const float*)d_in[1];
  // d_in[2] = batch (contiguous equal clouds; unused)
  const float* Wpos  = (const float*)d_in[3];
  const float* bpos  = (const float*)d_in[4];
  const float* Wattn = (const float*)d_in[5];
  const float* battn = (const float*)d_in[6];
  const float* Wval  = (const float*)d_in[7];
  const float* Wsrc  = (const float*)d_in[8];
  const float* Wdst  = (const float*)d_in[9];

  float* ws  = (float*)d_ws;
  float* A2  = ws;                        // 32768*64
  float* S2  = A2 + (size_t)NPTS * 64;    // 32768*64
  float* V   = S2 + (size_t)NPTS * 64;    // 32768*64
  float* WP2 = V + (size_t)NPTS * 64;     // 3*64
  float* bb  = WP2 + 192;                 // 64
  int*   nbr = (int*)(bb + 64);           // 32768*16 ints
  float* Hd  = (float*)(nbr + (size_t)NPTS * KNBR);  // 64*64
  float* Hs  = Hd + 4096;                 // 64*64
  float* out = (float*)d_out;

  prep_kernel<<<1, 1024, 0, stream>>>(Wpos, bpos, Wattn, battn, Wsrc, Wdst,
                                      Hd, Hs, WP2, bb);
  fused_gk_kernel<<<NGEMM + NKNN, 1024, 0, stream>>>(
      pos, x, Hd, Hs, Wval, nbr, A2, S2, V);
  edge_kernel<<<NPTS / 32, 512, 0, stream>>>(pos, nbr, A2, S2, V, WP2, bb,
                                             Wpos, bpos, out);
}

// Round 7
// 208.985 us; speedup vs baseline: 1.0831x; 1.0831x over previous
//
#include <hip/hip_runtime.h>
#include <math.h>

// Problem constants (fixed by reference)
#define BBATCH 16
#define NPC    2048          // points per cloud
#define KNBR   16            // knn k (self appended -> 17 edges)
#define NPTS   (BBATCH*NPC)  // 32768
#define NGEMM  512           // gemm blocks (64 rows each)
#define NKNN   512           // knn blocks (64 targets each)
#define BUFCAP 512

// ---------------------------------------------------------------------------
// prep_kernel: Hd = Wdst@Wattn, Hs = Wsrc@Wattn, WP2 = Wpos@Wattn,
//              bb = bpos@Wattn + battn.  One block.
// ---------------------------------------------------------------------------
__global__ __launch_bounds__(1024) void prep_kernel(
    const float* __restrict__ Wpos, const float* __restrict__ bpos,
    const float* __restrict__ Wattn, const float* __restrict__ battn,
    const float* __restrict__ Wsrc, const float* __restrict__ Wdst,
    float* __restrict__ Hd, float* __restrict__ Hs,
    float* __restrict__ WP2, float* __restrict__ bb) {
  __shared__ float sW[4096];
  __shared__ float sD[4096];
  __shared__ float sS[4096];
  int t = threadIdx.x;
  ((float4*)sW)[t] = ((const float4*)Wattn)[t];
  ((float4*)sD)[t] = ((const float4*)Wdst)[t];
  ((float4*)sS)[t] = ((const float4*)Wsrc)[t];
  __syncthreads();
  int c = t & 63, r0 = t >> 6;  // r0 = 0..15
#pragma unroll
  for (int q = 0; q < 4; ++q) {
    int r = r0 + 16 * q;
    float ad = 0.f, as = 0.f;
    for (int d = 0; d < 64; ++d) {
      float w = sW[d * 64 + c];
      ad += sD[r * 64 + d] * w;
      as += sS[r * 64 + d] * w;
    }
    Hd[r * 64 + c] = ad;
    Hs[r * 64 + c] = as;
  }
  if (t < 64) {
    for (int rr = 0; rr < 3; ++rr) {
      float a = 0.f;
      for (int d = 0; d < 64; ++d) a += Wpos[rr * 64 + d] * sW[d * 64 + t];
      WP2[rr * 64 + t] = a;
    }
    float a = battn[t];
    for (int d = 0; d < 64; ++d) a += bpos[d] * sW[d * 64 + t];
    bb[t] = a;
  }
}

// ---------------------------------------------------------------------------
// gemm_kernel: A2 = x@Hd, S2 = x@Hs, V = x@Wval.  64 rows per block.
// Exact R2 gemm-family body, standalone (must COMPLETE before knn_edge so
// edge's S2/V gathers are kernel-boundary-ordered -- dispatch-order safe).
// ---------------------------------------------------------------------------
__global__ __launch_bounds__(1024) void gemm_kernel(
    const float* __restrict__ x, const float* __restrict__ Hd,
    const float* __restrict__ Hs, const float* __restrict__ Wval,
    float* __restrict__ A2, float* __restrict__ S2, float* __restrict__ V) {
  __shared__ __align__(16) float smem[16384];  // 64 KB
  int t = threadIdx.x;
  int bid = blockIdx.x;
  int c = t & 63, g = t >> 6;

  float* R0 = smem;           // x tile
  float* R1 = smem + 4096;    // Hd
  float* R2 = smem + 8192;    // Hs
  float* R3 = smem + 12288;   // Wval
  ((float4*)R0)[t] = ((const float4*)(x + (size_t)bid * 64 * 64))[t];
  ((float4*)R1)[t] = ((const float4*)Hd)[t];
  ((float4*)R2)[t] = ((const float4*)Hs)[t];
  ((float4*)R3)[t] = ((const float4*)Wval)[t];
  __syncthreads();

  float v0 = 0, v1 = 0, v2 = 0, v3 = 0;
  float a0 = 0, a1 = 0, a2 = 0, a3 = 0;
  float s0 = 0, s1 = 0, s2 = 0, s3 = 0;
  const float4* xr0 = (const float4*)(R0 + (g * 4 + 0) * 64);
  const float4* xr1 = (const float4*)(R0 + (g * 4 + 1) * 64);
  const float4* xr2 = (const float4*)(R0 + (g * 4 + 2) * 64);
  const float4* xr3 = (const float4*)(R0 + (g * 4 + 3) * 64);
#pragma unroll 4
  for (int k4 = 0; k4 < 16; ++k4) {
    float4 q0 = xr0[k4], q1 = xr1[k4], q2 = xr2[k4], q3 = xr3[k4];
#pragma unroll
    for (int kk = 0; kk < 4; ++kk) {
      int k = k4 * 4 + kk;
      float wv = R3[k * 64 + c];
      float wa = R1[k * 64 + c];
      float ws = R2[k * 64 + c];
      float e0 = (kk == 0) ? q0.x : (kk == 1) ? q0.y : (kk == 2) ? q0.z : q0.w;
      float e1 = (kk == 0) ? q1.x : (kk == 1) ? q1.y : (kk == 2) ? q1.z : q1.w;
      float e2 = (kk == 0) ? q2.x : (kk == 1) ? q2.y : (kk == 2) ? q2.z : q2.w;
      float e3 = (kk == 0) ? q3.x : (kk == 1) ? q3.y : (kk == 2) ? q3.z : q3.w;
      v0 += e0 * wv; v1 += e1 * wv; v2 += e2 * wv; v3 += e3 * wv;
      a0 += e0 * wa; a1 += e1 * wa; a2 += e2 * wa; a3 += e3 * wa;
      s0 += e0 * ws; s1 += e1 * ws; s2 += e2 * ws; s3 += e3 * ws;
    }
  }
  size_t o0 = ((size_t)bid * 64 + g * 4 + 0) * 64 + c;
  V[o0] = v0; A2[o0] = a0; S2[o0] = s0;
  size_t o1 = o0 + 64;  V[o1] = v1; A2[o1] = a1; S2[o1] = s1;
  size_t o2 = o0 + 128; V[o2] = v2; A2[o2] = a2; S2[o2] = s2;
  size_t o3 = o0 + 192; V[o3] = v3; A2[o3] = a3; S2[o3] = s3;
}

// ---------------------------------------------------------------------------
// knn_edge_kernel: exact fp64 16-NN (byte-identical phases A/B/C + sort to
// the proven R2 knn family) + fused per-target edge epilogue:
//   - the 16 NN indices stay in registers (lanes 0..15) -> no nbr buffer
//   - neighbor pos reads are LDS broadcasts from the staged pos4
//   - edge's scattered S2/V gathers overlap other waves' knn VALU work
//     (complementary pipes; 32 waves/CU co-resident)
// ---------------------------------------------------------------------------
__global__ __launch_bounds__(1024) void knn_edge_kernel(
    const float* __restrict__ pos, const float* __restrict__ A2,
    const float* __restrict__ S2, const float* __restrict__ V,
    const float* __restrict__ WP2, const float* __restrict__ bbv,
    const float* __restrict__ Wpos, const float* __restrict__ bpos,
    float* __restrict__ out) {
  __shared__ __align__(16) char smem[49152];
  int t = threadIdx.x;
  int kb = blockIdx.x;  // 0..511
  int c = t & 63, g = t >> 6;

  float4* pos4 = (float4*)smem;                           // 32 KB
  unsigned short* buf = (unsigned short*)(smem + 32768);  // 16 KB (16w x 512)
  int cloud = kb >> 5;  // 32 blocks per cloud
  const float* pc = pos + (size_t)cloud * NPC * 3;
  for (int p = t; p < NPC; p += 1024)
    pos4[p] = make_float4(pc[3 * p], pc[3 * p + 1], pc[3 * p + 2], 0.f);
  __syncthreads();

  int w = g, lane = c;
  for (int u = 0; u < 4; ++u) {
    int lt = u * 16 + w;  // local target 0..63
    int gi = kb * 64 + lt;
    int ti = gi & (NPC - 1);
    float4 tp = pos4[ti];
    float tx = tp.x, ty = tp.y, tz = tp.z;

    // Phase A: fp32 d^2 -> exponent bucket (self lands in bucket 0, kept)
    int bkt[32];
#pragma unroll
    for (int cc = 0; cc < 32; ++cc) {
      int j = cc * 64 + lane;
      float4 q = pos4[j];
      float dx = tx - q.x, dy = ty - q.y, dz = tz - q.z;
      float d2 = dx * dx + dy * dy + dz * dz;
      int b = (int)(__float_as_uint(d2) >> 20) - 896;
      bkt[cc] = max(0, min(255, b));
    }

    // Phase B: smallest T with count(bkt<=T) >= 17 (16 real + self)
    int lo = 0, hi = 255;
    for (int it = 0; it < 8; ++it) {
      int mid = (lo + hi) >> 1;
      int cnt = 0;
#pragma unroll
      for (int cc = 0; cc < 32; ++cc)
        cnt += (int)__popcll(__ballot(bkt[cc] <= mid));
      if (cnt >= 17) hi = mid; else lo = mid + 1;
    }
    int Tp1 = min(hi + 1, 255);

    // Phase C: atomic-free compaction (ballot + mbcnt prefix)
    int base = 0;
#pragma unroll
    for (int cc = 0; cc < 32; ++cc) {
      bool f = (bkt[cc] <= Tp1);
      unsigned long long mm = __ballot(f);
      unsigned int pre = __builtin_amdgcn_mbcnt_hi(
          (unsigned)(mm >> 32), __builtin_amdgcn_mbcnt_lo((unsigned)mm, 0u));
      if (f) {
        int p = base + (int)pre;
        if (p < BUFCAP) buf[w * BUFCAP + p] = (unsigned short)(cc * 64 + lane);
      }
      base += (int)__popcll(mm);
    }
    int n = min(base, BUFCAP);
    double txd = (double)tx, tyd = (double)ty, tzd = (double)tz;

    int jv;  // per-lane: lane e (<16) holds the e-th NN index after knn
    if (n <= 64) {
      // fp64 exact keys (bit-match numpy f64 ((dx^2+dy^2)+dz^2)), bitonic-64
      unsigned long long gb = 0xFFFFFFFFFFFFFFFFull;
      int gj = 0x40000000 + lane;
      if (lane < n) {
        int j = buf[w * BUFCAP + lane];
        if (j != ti) {
          float4 q = pos4[j];
          double dx = __dsub_rn(txd, (double)q.x);
          double dy = __dsub_rn(tyd, (double)q.y);
          double dz = __dsub_rn(tzd, (double)q.z);
          double d2 = __dadd_rn(__dadd_rn(__dmul_rn(dx, dx), __dmul_rn(dy, dy)),
                                __dmul_rn(dz, dz));
          gb = (unsigned long long)__double_as_longlong(d2);
          gj = j;
        }
      }
      for (int k = 2; k <= 64; k <<= 1) {
        for (int jj = k >> 1; jj > 0; jj >>= 1) {
          unsigned long long ob = __shfl_xor(gb, jj);
          int oj = __shfl_xor(gj, jj);
          bool keepmin = (((lane & k) == 0) == ((lane & jj) == 0));
          bool less = (ob < gb) || (ob == gb && oj < gj);
          if (keepmin == less) { gb = ob; gj = oj; }
        }
      }
      jv = gj;
    } else {
      // rare fallback: extraction over buffered set (n <= 512)
      unsigned long long kb2[8];
      int id2[8];
#pragma unroll
      for (int r = 0; r < 8; ++r) {
        int e = r * 64 + lane;
        kb2[r] = 0xFFFFFFFFFFFFFFFFull;
        id2[r] = 0x40000000 + e;
        if (e < n) {
          int j = buf[w * BUFCAP + e];
          if (j != ti) {
            float4 q = pos4[j];
            double dx = __dsub_rn(txd, (double)q.x);
            double dy = __dsub_rn(tyd, (double)q.y);
            double dz = __dsub_rn(tzd, (double)q.z);
            double d2 = __dadd_rn(
                __dadd_rn(__dmul_rn(dx, dx), __dmul_rn(dy, dy)),
                __dmul_rn(dz, dz));
            kb2[r] = (unsigned long long)__double_as_longlong(d2);
            id2[r] = j;
          }
        }
      }
      jv = 0;
      for (int r = 0; r < KNBR; ++r) {
        unsigned long long lb = kb2[0];
        int lj = id2[0];
#pragma unroll
        for (int cc = 1; cc < 8; ++cc)
          if (kb2[cc] < lb || (kb2[cc] == lb && id2[cc] < lj)) {
            lb = kb2[cc]; lj = id2[cc];
          }
        unsigned long long gb2 = lb;
        int gj2 = lj;
#pragma unroll
        for (int d = 32; d >= 1; d >>= 1) {
          unsigned long long ob = __shfl_xor(gb2, d);
          int oj = __shfl_xor(gj2, d);
          if (ob < gb2 || (ob == gb2 && oj < gj2)) { gb2 = ob; gj2 = oj; }
        }
#pragma unroll
        for (int cc = 0; cc < 8; ++cc)
          if (id2[cc] == gj2) kb2[cc] = 0xFFFFFFFFFFFFFFFFull;
        if (lane == r) jv = gj2;
      }
    }

    // ---- fused edge epilogue: 17-way online softmax, lane = channel ----
    {
      size_t cbase = (size_t)cloud * NPC;
      float a2v = A2[((size_t)gi) * 64 + lane];
      float wp0 = WP2[lane], wp1 = WP2[64 + lane], wp2 = WP2[128 + lane];
      float bbc = bbv[lane];
      float u0 = Wpos[lane], u1 = Wpos[64 + lane], u2 = Wpos[128 + lane];
      float bpc = bpos[lane];
      float m = -1e30f, den = 0.f, acc = 0.f;
#pragma unroll
      for (int e = 0; e < 17; ++e) {
        int j = (e < 16) ? __shfl(jv, e) : ti;
        float4 q = pos4[j];  // uniform-address LDS broadcast
        float dx = tx - q.x, dy = ty - q.y, dz = tz - q.z;
        size_t jrow = (cbase + j) * 64 + lane;
        float s2 = S2[jrow];
        float v = V[jrow];
        float lg = a2v - s2 + dx * wp0 + dy * wp1 + dz * wp2 + bbc;
        float vl = v + dx * u0 + dy * u1 + dz * u2 + bpc;
        float mn = fmaxf(m, lg);
        float sc = __expf(m - mn);
        float wgt = __expf(lg - mn);
        den = den * sc + wgt;
        acc = acc * sc + wgt * vl;
        m = mn;
      }
      out[((size_t)gi) * 64 + lane] = acc / den;
    }
  }
}

// ---------------------------------------------------------------------------
extern "C" void kernel_launch(void* const* d_in, const int* in_sizes, int n_in,
                              void* d_out, int out_size, void* d_ws, size_t ws_size,
                              hipStream_t stream) {
  const float* x     = (const float*)d_in[0];
  const float* pos   = (const float*)d_in[1];
  // d_in[2] = batch (contiguous equal clouds; unused)
  const float* Wpos  = (const float*)d_in[3];
  const float* bpos  = (const float*)d_in[4];
  const float* Wattn = (const float*)d_in[5];
  const float* battn = (const float*)d_in[6];
  const float* Wval  = (const float*)d_in[7];
  const float* Wsrc  = (const float*)d_in[8];
  const float* Wdst  = (const float*)d_in[9];

  float* ws  = (float*)d_ws;
  float* A2  = ws;                        // 32768*64
  float* S2  = A2 + (size_t)NPTS * 64;    // 32768*64
  float* V   = S2 + (size_t)NPTS * 64;    // 32768*64
  float* WP2 = V + (size_t)NPTS * 64;     // 3*64
  float* bb  = WP2 + 192;                 // 64
  float* Hd  = bb + 64;                   // 64*64
  float* Hs  = Hd + 4096;                 // 64*64
  float* out = (float*)d_out;

  prep_kernel<<<1, 1024, 0, stream>>>(Wpos, bpos, Wattn, battn, Wsrc, Wdst,
                                      Hd, Hs, WP2, bb);
  gemm_kernel<<<NGEMM, 1024, 0, stream>>>(x, Hd, Hs, Wval, A2, S2, V);
  knn_edge_kernel<<<NKNN, 1024, 0, stream>>>(pos, A2, S2, V, WP2, bb,
                                             Wpos, bpos, out);
}

// Round 8
// 202.314 us; speedup vs baseline: 1.1189x; 1.0330x over previous
//
#include <hip/hip_runtime.h>
#include <hip/hip_cooperative_groups.h>
#include <math.h>

namespace cg = cooperative_groups;

// Problem constants (fixed by reference)
#define BBATCH 16
#define NPC    2048          // points per cloud
#define KNBR   16            // knn k (self appended -> 17 edges)
#define NPTS   (BBATCH*NPC)  // 32768
#define NGEMM  512           // gemm blocks (64 rows each)
#define NKNN   512           // knn blocks (64 targets each)
#define BUFCAP 512

// ===========================================================================
// Shared device bodies (exact R7-proven code), used by both the cooperative
// mega-kernel and the 3-launch fallback.
// ===========================================================================
__device__ __forceinline__ void prep_body(
    char* smem, int t,
    const float* __restrict__ Wpos, const float* __restrict__ bpos,
    const float* __restrict__ Wattn, const float* __restrict__ battn,
    const float* __restrict__ Wsrc, const float* __restrict__ Wdst,
    float* __restrict__ Hd, float* __restrict__ Hs,
    float* __restrict__ WP2, float* __restrict__ bb) {
  float* sW = (float*)smem;             // 16 KB
  float* sD = (float*)(smem + 16384);   // 16 KB
  float* sS = (float*)(smem + 32768);   // 16 KB
  ((float4*)sW)[t] = ((const float4*)Wattn)[t];
  ((float4*)sD)[t] = ((const float4*)Wdst)[t];
  ((float4*)sS)[t] = ((const float4*)Wsrc)[t];
  __syncthreads();
  int c = t & 63, r0 = t >> 6;  // r0 = 0..15
#pragma unroll
  for (int q = 0; q < 4; ++q) {
    int r = r0 + 16 * q;
    float ad = 0.f, as = 0.f;
    for (int d = 0; d < 64; ++d) {
      float w = sW[d * 64 + c];
      ad += sD[r * 64 + d] * w;
      as += sS[r * 64 + d] * w;
    }
    Hd[r * 64 + c] = ad;
    Hs[r * 64 + c] = as;
  }
  if (t < 64) {
    for (int rr = 0; rr < 3; ++rr) {
      float a = 0.f;
      for (int d = 0; d < 64; ++d) a += Wpos[rr * 64 + d] * sW[d * 64 + t];
      WP2[rr * 64 + t] = a;
    }
    float a = battn[t];
    for (int d = 0; d < 64; ++d) a += bpos[d] * sW[d * 64 + t];
    bb[t] = a;
  }
}

__device__ __forceinline__ void gemm_body(
    char* smemc, int t, int bid,
    const float* __restrict__ x, const float* __restrict__ Hd,
    const float* __restrict__ Hs, const float* __restrict__ Wval,
    float* __restrict__ A2, float* __restrict__ S2, float* __restrict__ V) {
  float* smem = (float*)smemc;
  int c = t & 63, g = t >> 6;
  float* R0 = smem;           // x tile
  float* R1 = smem + 4096;    // Hd
  float* R2 = smem + 8192;    // Hs
  float* R3 = smem + 12288;   // Wval
  ((float4*)R0)[t] = ((const float4*)(x + (size_t)bid * 64 * 64))[t];
  ((float4*)R1)[t] = ((const float4*)Hd)[t];
  ((float4*)R2)[t] = ((const float4*)Hs)[t];
  ((float4*)R3)[t] = ((const float4*)Wval)[t];
  __syncthreads();

  float v0 = 0, v1 = 0, v2 = 0, v3 = 0;
  float a0 = 0, a1 = 0, a2 = 0, a3 = 0;
  float s0 = 0, s1 = 0, s2 = 0, s3 = 0;
  const float4* xr0 = (const float4*)(R0 + (g * 4 + 0) * 64);
  const float4* xr1 = (const float4*)(R0 + (g * 4 + 1) * 64);
  const float4* xr2 = (const float4*)(R0 + (g * 4 + 2) * 64);
  const float4* xr3 = (const float4*)(R0 + (g * 4 + 3) * 64);
#pragma unroll 4
  for (int k4 = 0; k4 < 16; ++k4) {
    float4 q0 = xr0[k4], q1 = xr1[k4], q2 = xr2[k4], q3 = xr3[k4];
#pragma unroll
    for (int kk = 0; kk < 4; ++kk) {
      int k = k4 * 4 + kk;
      float wv = R3[k * 64 + c];
      float wa = R1[k * 64 + c];
      float ws = R2[k * 64 + c];
      float e0 = (kk == 0) ? q0.x : (kk == 1) ? q0.y : (kk == 2) ? q0.z : q0.w;
      float e1 = (kk == 0) ? q1.x : (kk == 1) ? q1.y : (kk == 2) ? q1.z : q1.w;
      float e2 = (kk == 0) ? q2.x : (kk == 1) ? q2.y : (kk == 2) ? q2.z : q2.w;
      float e3 = (kk == 0) ? q3.x : (kk == 1) ? q3.y : (kk == 2) ? q3.z : q3.w;
      v0 += e0 * wv; v1 += e1 * wv; v2 += e2 * wv; v3 += e3 * wv;
      a0 += e0 * wa; a1 += e1 * wa; a2 += e2 * wa; a3 += e3 * wa;
      s0 += e0 * ws; s1 += e1 * ws; s2 += e2 * ws; s3 += e3 * ws;
    }
  }
  size_t o0 = ((size_t)bid * 64 + g * 4 + 0) * 64 + c;
  V[o0] = v0; A2[o0] = a0; S2[o0] = s0;
  size_t o1 = o0 + 64;  V[o1] = v1; A2[o1] = a1; S2[o1] = s1;
  size_t o2 = o0 + 128; V[o2] = v2; A2[o2] = a2; S2[o2] = s2;
  size_t o3 = o0 + 192; V[o3] = v3; A2[o3] = a3; S2[o3] = s3;
}

__device__ __forceinline__ void knn_edge_body(
    char* smem, int t, int kb,
    const float* __restrict__ pos, const float* __restrict__ A2,
    const float* __restrict__ S2, const float* __restrict__ V,
    const float* __restrict__ WP2, const float* __restrict__ bbv,
    const float* __restrict__ Wpos, const float* __restrict__ bpos,
    float* __restrict__ out) {
  int c = t & 63, g = t >> 6;
  float4* pos4 = (float4*)smem;                           // 32 KB
  unsigned short* buf = (unsigned short*)(smem + 32768);  // 16 KB (16w x 512)
  int cloud = kb >> 5;  // 32 blocks per cloud
  const float* pc = pos + (size_t)cloud * NPC * 3;
  for (int p = t; p < NPC; p += 1024)
    pos4[p] = make_float4(pc[3 * p], pc[3 * p + 1], pc[3 * p + 2], 0.f);
  __syncthreads();

  int w = g, lane = c;
  for (int u = 0; u < 4; ++u) {
    int lt = u * 16 + w;  // local target 0..63
    int gi = kb * 64 + lt;
    int ti = gi & (NPC - 1);
    float4 tp = pos4[ti];
    float tx = tp.x, ty = tp.y, tz = tp.z;

    // Phase A: fp32 d^2 -> exponent bucket (self lands in bucket 0, kept)
    int bkt[32];
#pragma unroll
    for (int cc = 0; cc < 32; ++cc) {
      int j = cc * 64 + lane;
      float4 q = pos4[j];
      float dx = tx - q.x, dy = ty - q.y, dz = tz - q.z;
      float d2 = dx * dx + dy * dy + dz * dz;
      int b = (int)(__float_as_uint(d2) >> 20) - 896;
      bkt[cc] = max(0, min(255, b));
    }

    // Phase B: smallest T with count(bkt<=T) >= 17 (16 real + self)
    int lo = 0, hi = 255;
    for (int it = 0; it < 8; ++it) {
      int mid = (lo + hi) >> 1;
      int cnt = 0;
#pragma unroll
      for (int cc = 0; cc < 32; ++cc)
        cnt += (int)__popcll(__ballot(bkt[cc] <= mid));
      if (cnt >= 17) hi = mid; else lo = mid + 1;
    }
    int Tp1 = min(hi + 1, 255);

    // Phase C: atomic-free compaction (ballot + mbcnt prefix)
    int base = 0;
#pragma unroll
    for (int cc = 0; cc < 32; ++cc) {
      bool f = (bkt[cc] <= Tp1);
      unsigned long long mm = __ballot(f);
      unsigned int pre = __builtin_amdgcn_mbcnt_hi(
          (unsigned)(mm >> 32), __builtin_amdgcn_mbcnt_lo((unsigned)mm, 0u));
      if (f) {
        int p = base + (int)pre;
        if (p < BUFCAP) buf[w * BUFCAP + p] = (unsigned short)(cc * 64 + lane);
      }
      base += (int)__popcll(mm);
    }
    int n = min(base, BUFCAP);
    double txd = (double)tx, tyd = (double)ty, tzd = (double)tz;

    int jv;  // per-lane: lane e (<16) holds the e-th NN index after knn
    if (n <= 64) {
      unsigned long long gb = 0xFFFFFFFFFFFFFFFFull;
      int gj = 0x40000000 + lane;
      if (lane < n) {
        int j = buf[w * BUFCAP + lane];
        if (j != ti) {
          float4 q = pos4[j];
          double dx = __dsub_rn(txd, (double)q.x);
          double dy = __dsub_rn(tyd, (double)q.y);
          double dz = __dsub_rn(tzd, (double)q.z);
          double d2 = __dadd_rn(__dadd_rn(__dmul_rn(dx, dx), __dmul_rn(dy, dy)),
                                __dmul_rn(dz, dz));
          gb = (unsigned long long)__double_as_longlong(d2);
          gj = j;
        }
      }
      for (int k = 2; k <= 64; k <<= 1) {
        for (int jj = k >> 1; jj > 0; jj >>= 1) {
          unsigned long long ob = __shfl_xor(gb, jj);
          int oj = __shfl_xor(gj, jj);
          bool keepmin = (((lane & k) == 0) == ((lane & jj) == 0));
          bool less = (ob < gb) || (ob == gb && oj < gj);
          if (keepmin == less) { gb = ob; gj = oj; }
        }
      }
      jv = gj;
    } else {
      unsigned long long kb2[8];
      int id2[8];
#pragma unroll
      for (int r = 0; r < 8; ++r) {
        int e = r * 64 + lane;
        kb2[r] = 0xFFFFFFFFFFFFFFFFull;
        id2[r] = 0x40000000 + e;
        if (e < n) {
          int j = buf[w * BUFCAP + e];
          if (j != ti) {
            float4 q = pos4[j];
            double dx = __dsub_rn(txd, (double)q.x);
            double dy = __dsub_rn(tyd, (double)q.y);
            double dz = __dsub_rn(tzd, (double)q.z);
            double d2 = __dadd_rn(
                __dadd_rn(__dmul_rn(dx, dx), __dmul_rn(dy, dy)),
                __dmul_rn(dz, dz));
            kb2[r] = (unsigned long long)__double_as_longlong(d2);
            id2[r] = j;
          }
        }
      }
      jv = 0;
      for (int r = 0; r < KNBR; ++r) {
        unsigned long long lb = kb2[0];
        int lj = id2[0];
#pragma unroll
        for (int cc = 1; cc < 8; ++cc)
          if (kb2[cc] < lb || (kb2[cc] == lb && id2[cc] < lj)) {
            lb = kb2[cc]; lj = id2[cc];
          }
        unsigned long long gb2 = lb;
        int gj2 = lj;
#pragma unroll
        for (int d = 32; d >= 1; d >>= 1) {
          unsigned long long ob = __shfl_xor(gb2, d);
          int oj = __shfl_xor(gj2, d);
          if (ob < gb2 || (ob == gb2 && oj < gj2)) { gb2 = ob; gj2 = oj; }
        }
#pragma unroll
        for (int cc = 0; cc < 8; ++cc)
          if (id2[cc] == gj2) kb2[cc] = 0xFFFFFFFFFFFFFFFFull;
        if (lane == r) jv = gj2;
      }
    }

    // ---- fused edge epilogue: 17-way online softmax, lane = channel ----
    {
      size_t cbase = (size_t)cloud * NPC;
      float a2v = A2[((size_t)gi) * 64 + lane];
      float wp0 = WP2[lane], wp1 = WP2[64 + lane], wp2 = WP2[128 + lane];
      float bbc = bbv[lane];
      float u0 = Wpos[lane], u1 = Wpos[64 + lane], u2 = Wpos[128 + lane];
      float bpc = bpos[lane];
      float m = -1e30f, den = 0.f, acc = 0.f;
#pragma unroll
      for (int e = 0; e < 17; ++e) {
        int j = (e < 16) ? __shfl(jv, e) : ti;
        float4 q = pos4[j];  // uniform-address LDS broadcast
        float dx = tx - q.x, dy = ty - q.y, dz = tz - q.z;
        size_t jrow = (cbase + j) * 64 + lane;
        float s2 = S2[jrow];
        float v = V[jrow];
        float lg = a2v - s2 + dx * wp0 + dy * wp1 + dz * wp2 + bbc;
        float vl = v + dx * u0 + dy * u1 + dz * u2 + bpc;
        float mn = fmaxf(m, lg);
        float sc = __expf(m - mn);
        float wgt = __expf(lg - mn);
        den = den * sc + wgt;
        acc = acc * sc + wgt * vl;
        m = mn;
      }
      out[((size_t)gi) * 64 + lane] = acc / den;
    }
  }
}

// ===========================================================================
// Cooperative mega-kernel: prep (block 0) -> grid.sync -> gemm -> grid.sync
// -> knn+edge.  512 blocks x 1024 threads = exactly-full machine (2/CU,
// 128 KB LDS/CU).  grid.sync provides the device-scope ordering that makes
// gemm's S2/V visible to edge's cross-XCD gathers (G16-sanctioned).
// ===========================================================================
__global__ __launch_bounds__(1024) void mega_kernel(
    const float* __restrict__ pos, const float* __restrict__ x,
    const float* __restrict__ Wpos, const float* __restrict__ bpos,
    const float* __restrict__ Wattn, const float* __restrict__ battn,
    const float* __restrict__ Wval, const float* __restrict__ Wsrc,
    const float* __restrict__ Wdst,
    float* __restrict__ A2, float* __restrict__ S2, float* __restrict__ V,
    float* __restrict__ WP2, float* __restrict__ bb,
    float* __restrict__ Hd, float* __restrict__ Hs,
    float* __restrict__ out) {
  __shared__ __align__(16) char smem[65536];
  cg::grid_group grid = cg::this_grid();
  int t = threadIdx.x;
  int bid = blockIdx.x;

  if (bid == 0)
    prep_body(smem, t, Wpos, bpos, Wattn, battn, Wsrc, Wdst, Hd, Hs, WP2, bb);
  grid.sync();

  gemm_body(smem, t, bid, x, Hd, Hs, Wval, A2, S2, V);
  grid.sync();

  knn_edge_body(smem, t, bid, pos, A2, S2, V, WP2, bb, Wpos, bpos, out);
}

// ===========================================================================
// Fallback kernels (exact R7 structure) if cooperative residency check fails.
// ===========================================================================
__global__ __launch_bounds__(1024) void prep_kernel(
    const float* __restrict__ Wpos, const float* __restrict__ bpos,
    const float* __restrict__ Wattn, const float* __restrict__ battn,
    const float* __restrict__ Wsrc, const float* __restrict__ Wdst,
    float* __restrict__ Hd, float* __restrict__ Hs,
    float* __restrict__ WP2, float* __restrict__ bb) {
  __shared__ __align__(16) char smem[49152];
  prep_body(smem, threadIdx.x, Wpos, bpos, Wattn, battn, Wsrc, Wdst,
            Hd, Hs, WP2, bb);
}

__global__ __launch_bounds__(1024) void gemm_kernel(
    const float* __restrict__ x, const float* __restrict__ Hd,
    const float* __restrict__ Hs, const float* __restrict__ Wval,
    float* __restrict__ A2, float* __restrict__ S2, float* __restrict__ V) {
  __shared__ __align__(16) char smem[65536];
  gemm_body(smem, threadIdx.x, blockIdx.x, x, Hd, Hs, Wval, A2, S2, V);
}

__global__ __launch_bounds__(1024) void knn_edge_kernel(
    const float* __restrict__ pos, const float* __restrict__ A2,
    const float* __restrict__ S2, const float* __restrict__ V,
    const float* __restrict__ WP2, const float* __restrict__ bbv,
    const float* __restrict__ Wpos, const float* __restrict__ bpos,
    float* __restrict__ out) {
  __shared__ __align__(16) char smem[49152];
  knn_edge_body(smem, threadIdx.x, blockIdx.x, pos, A2, S2, V, WP2, bbv,
                Wpos, bpos, out);
}

// ===========================================================================
extern "C" void kernel_launch(void* const* d_in, const int* in_sizes, int n_in,
                              void* d_out, int out_size, void* d_ws, size_t ws_size,
                              hipStream_t stream) {
  const float* x     = (const float*)d_in[0];
  const float* pos   = (const float*)d_in[1];
  // d_in[2] = batch (contiguous equal clouds; unused)
  const float* Wpos  = (const float*)d_in[3];
  const float* bpos  = (const float*)d_in[4];
  const float* Wattn = (const float*)d_in[5];
  const float* battn = (const float*)d_in[6];
  const float* Wval  = (const float*)d_in[7];
  const float* Wsrc  = (const float*)d_in[8];
  const float* Wdst  = (const float*)d_in[9];

  float* ws  = (float*)d_ws;
  float* A2  = ws;                        // 32768*64
  float* S2  = A2 + (size_t)NPTS * 64;    // 32768*64
  float* V   = S2 + (size_t)NPTS * 64;    // 32768*64
  float* WP2 = V + (size_t)NPTS * 64;     // 3*64
  float* bb  = WP2 + 192;                 // 64
  float* Hd  = bb + 64;                   // 64*64
  float* Hs  = Hd + 4096;                 // 64*64
  float* out = (float*)d_out;

  // One-time co-residency check: mega needs 2 blocks/CU (512 blocks total).
  static int coop_ok = -1;
  if (coop_ok < 0) {
    int nb = 0;
    hipError_t e =
        hipOccupancyMaxActiveBlocksPerMultiprocessor(&nb, mega_kernel, 1024, 0);
    coop_ok = (e == hipSuccess && nb >= 2) ? 1 : 0;
  }

  if (coop_ok) {
    void* args[] = {
        (void*)&pos, (void*)&x, (void*)&Wpos, (void*)&bpos, (void*)&Wattn,
        (void*)&battn, (void*)&Wval, (void*)&Wsrc, (void*)&Wdst,
        (void*)&A2, (void*)&S2, (void*)&V, (void*)&WP2, (void*)&bb,
        (void*)&Hd, (void*)&Hs, (void*)&out};
    hipLaunchCooperativeKernel((const void*)mega_kernel, dim3(NKNN),
                               dim3(1024), args, 0, stream);
  } else {
    prep_kernel<<<1, 1024, 0, stream>>>(Wpos, bpos, Wattn, battn, Wsrc, Wdst,
                                        Hd, Hs, WP2, bb);
    gemm_kernel<<<NGEMM, 1024, 0, stream>>>(x, Hd, Hs, Wval, A2, S2, V);
    knn_edge_kernel<<<NKNN, 1024, 0, stream>>>(pos, A2, S2, V, WP2, bb,
                                               Wpos, bpos, out);
  }
}